// Round 23
// baseline (545.821 us; speedup 1.0000x reference)
//
#include <hip/hip_runtime.h>
#include <math.h>

// Problem constants (fixed by the reference setup_inputs)
#define BATCH 32
#define CH    192
#define TFEAT 2048
#define TTXT  512
#define NEGINF (-1e9f)

#define ATTN_ELEMS ((size_t)BATCH * TFEAT * TTXT)   // 33,554,432
#define DUR_OFF    ATTN_ELEMS
#define NEG_OFF    (ATTN_ELEMS + (size_t)BATCH * TTXT)

typedef short bf16x8 __attribute__((ext_vector_type(8)));   // 8 bf16 = 4 VGPR
typedef float f32x16 __attribute__((ext_vector_type(16)));  // 32x32 acc

__device__ __forceinline__ void gload_lds16h(const unsigned short* g,
                                             unsigned short* l) {
  __builtin_amdgcn_global_load_lds(
      (const __attribute__((address_space(1))) void*)g,
      (__attribute__((address_space(3))) void*)l, 16, 0, 0);
}

#define VMCNT(n) asm volatile("s_waitcnt vmcnt(" #n ")" ::: "memory")

__device__ __forceinline__ unsigned short f2b16(float f) {   // RNE bf16
  unsigned u = __float_as_uint(f);
  return (unsigned short)((u + 0x7FFFu + ((u >> 16) & 1u)) >> 16);
}

// ---------------------------------------------------------------------------
// Kernel TA: At2 = fragment-ready bf16 of A = [z | z^2] (M=2048, K=384).
// ---------------------------------------------------------------------------
__global__ __launch_bounds__(256)
void k_transA(const float* __restrict__ z_p, unsigned short* __restrict__ At2) {
  __shared__ float zt[CH][33];
  int b = blockIdx.x >> 6, tblk = blockIdx.x & 63;
  int tid = threadIdx.x;
  int t0 = tblk * 32;
  for (int i = tid; i < CH * 32; i += 256) {
    int c = i >> 5, m = i & 31;
    zt[c][m] = z_p[((size_t)b * CH + c) * TFEAT + t0 + m];
  }
  __syncthreads();
  unsigned short* out = At2 + (size_t)(b * 64 + tblk) * 24 * 512;
  for (int o = tid; o < 24 * 512; o += 256) {
    int kq = o >> 9, rem = o & 511;
    int lane = rem >> 3, j = rem & 7;
    int m = lane & 31, kh = lane >> 5;
    int k = kq * 16 + kh * 8 + j;
    float f;
    if (k < CH) f = zt[k][m];
    else { float z = zt[k - CH][m]; f = z * z; }
    out[o] = f2b16(f);
  }
}

// ---------------------------------------------------------------------------
// Kernel TB: Bt2 = fragment-ready bf16 of B = [W1 ; W2] (K=384, N=512).
// ---------------------------------------------------------------------------
__global__ __launch_bounds__(256)
void k_transB(const float* __restrict__ m_p, const float* __restrict__ logs_p,
              unsigned short* __restrict__ Bt2) {
  __shared__ float w1t[CH][33];
  __shared__ float w2t[CH][33];
  int b = blockIdx.x >> 4, sblk = blockIdx.x & 15;
  int tid = threadIdx.x;
  int s0 = sblk * 32;
  for (int i = tid; i < CH * 32; i += 256) {
    int c = i >> 5, n = i & 31;
    size_t idx = ((size_t)b * CH + c) * TTXT + s0 + n;
    float m = m_p[idx];
    float r = __expf(-2.0f * logs_p[idx]);
    w1t[c][n] = m * r;
    w2t[c][n] = -0.5f * r;
  }
  __syncthreads();
  unsigned short* out = Bt2 + (size_t)(b * 16 + sblk) * 24 * 512;
  for (int o = tid; o < 24 * 512; o += 256) {
    int kq = o >> 9, rem = o & 511;
    int lane = rem >> 3, j = rem & 7;
    int n = lane & 31, kh = lane >> 5;
    int k = kq * 16 + kh * 8 + j;
    float f = (k < CH) ? w1t[k][n] : w2t[k - CH][n];
    out[o] = f2b16(f);
  }
}

// ---------------------------------------------------------------------------
// Kernel A: cadd[b][s] = sum_c(-0.5*log(2pi) - logs) + sum_c(-0.5*m^2*r)
// ---------------------------------------------------------------------------
__global__ void k_cadd(const float* __restrict__ m_p,
                       const float* __restrict__ logs_p,
                       float* __restrict__ cadd) {
  int gid = blockIdx.x * 256 + threadIdx.x;        // 0 .. 16383
  int b = gid >> 9, s = gid & (TTXT - 1);
  const float* mp = m_p    + (size_t)b * CH * TTXT + s;
  const float* lp = logs_p + (size_t)b * CH * TTXT + s;
  float acc = -0.5f * 1.8378770664093453f * (float)CH;   // -C/2 * log(2*pi)
  #pragma unroll 4
  for (int c = 0; c < CH; ++c) {
    float l = lp[(size_t)c * TTXT];
    float m = mp[(size_t)c * TTXT];
    float r = __expf(-2.0f * l);
    acc -= l + 0.5f * m * m * r;
  }
  cadd[gid] = acc;
}

// ---------------------------------------------------------------------------
// Kernel B: bf16 MFMA GEMM (R19, UNCHANGED).
// ---------------------------------------------------------------------------
__global__ __launch_bounds__(512)
void k_mf(const unsigned short* __restrict__ At2,
          const unsigned short* __restrict__ Bt2,
          const float* __restrict__ cadd,
          float* __restrict__ neg,
          unsigned short* __restrict__ negh) {
  int blk = (blockIdx.x & 7) * 128 + (blockIdx.x >> 3);
  int sb = blk & 1;            // 512/256 = 2 col-blocks
  int tb = (blk >> 1) & 15;    // 2048/128 = 16 row-blocks
  int b  = blk >> 5;
  int tid = threadIdx.x, lane = tid & 63, w = tid >> 6;
  int rg = w >> 2, cg = w & 3;
  int trow0 = tb * 128 + rg * 64;
  int scol0 = sb * 256 + cg * 64;

  const unsigned short* ap0 = At2 + ((size_t)(b * 64 + (trow0 >> 5)) * 24) * 512 + lane * 8;
  const unsigned short* ap1 = ap0 + (size_t)24 * 512;
  const unsigned short* bp0 = Bt2 + ((size_t)(b * 16 + (scol0 >> 5)) * 24) * 512 + lane * 8;
  const unsigned short* bp1 = bp0 + (size_t)24 * 512;

  f32x16 acc00, acc01, acc10, acc11;
  #pragma unroll
  for (int r = 0; r < 16; ++r) { acc00[r] = 0.f; acc01[r] = 0.f; acc10[r] = 0.f; acc11[r] = 0.f; }

  bf16x8 a0A, a1A, b0A, b1A;
  bf16x8 a0B, a1B, b0B, b1B;

  auto LDA = [&](bf16x8& x0, bf16x8& x1, bf16x8& y0, bf16x8& y1, int kq) {
    x0 = *(const bf16x8*)(ap0 + (size_t)kq * 512);
    x1 = *(const bf16x8*)(ap1 + (size_t)kq * 512);
    y0 = *(const bf16x8*)(bp0 + (size_t)kq * 512);
    y1 = *(const bf16x8*)(bp1 + (size_t)kq * 512);
  };
  auto FMA = [&](bf16x8& x0, bf16x8& x1, bf16x8& y0, bf16x8& y1) {
    acc00 = __builtin_amdgcn_mfma_f32_32x32x16_bf16(x0, y0, acc00, 0, 0, 0);
    acc01 = __builtin_amdgcn_mfma_f32_32x32x16_bf16(x0, y1, acc01, 0, 0, 0);
    acc10 = __builtin_amdgcn_mfma_f32_32x32x16_bf16(x1, y0, acc10, 0, 0, 0);
    acc11 = __builtin_amdgcn_mfma_f32_32x32x16_bf16(x1, y1, acc11, 0, 0, 0);
  };

  LDA(a0A, a1A, b0A, b1A, 0);
  #pragma unroll
  for (int kq = 0; kq < 24; kq += 2) {
    LDA(a0B, a1B, b0B, b1B, kq + 1);
    FMA(a0A, a1A, b0A, b1A);
    __builtin_amdgcn_sched_barrier(0);
    if (kq + 2 < 24) LDA(a0A, a1A, b0A, b1A, kq + 2);
    FMA(a0B, a1B, b0B, b1B);
    __builtin_amdgcn_sched_barrier(0);
  }

  #pragma unroll
  for (int ti = 0; ti < 2; ++ti) {
    #pragma unroll
    for (int tj = 0; tj < 2; ++tj) {
      const f32x16& v = (ti == 0) ? ((tj == 0) ? acc00 : acc01)
                                  : ((tj == 0) ? acc10 : acc11);
      int s = scol0 + tj * 32 + (lane & 31);
      float cv = cadd[b * TTXT + s];
      int tB = trow0 + ti * 32 + 4 * (lane >> 5);
      float* np_ = neg + (size_t)b * TFEAT * TTXT + s;
      #pragma unroll
      for (int r = 0; r < 16; ++r) {
        int t = tB + (r & 3) + 8 * (r >> 2);
        float o = v[r] + cv;
        np_[(size_t)t * TTXT] = o;
        negh[(((size_t)b * 128 + (t >> 4)) * 8 + (s >> 6)) * 1024
             + (t & 15) * 64 + (s & 63)] = f2b16(o);
      }
    }
  }
}

// ---------------------------------------------------------------------------
// Kernel C (R23): BARRIER-FREE dataflow DP. The skew's only dependency is
// adjacent-wave (w-1's window i -> w's window i); the 136 full 8-wave
// s_barrier convergences (never isolated before) are replaced by point-to-
// point LDS progress flags + a full bndfull[128][8][16] array (no ring, no
// overwrite, unbounded skew safe). Row chain / ring staging / R21 vmcnt
// counts / gbits / backtrack verbatim R22 -> bit-exact path.
// ---------------------------------------------------------------------------
#define KROWS 16
#define NWIN  (TFEAT / KROWS)     // 128 windows
#define NMASKW (TTXT / KROWS)     // 32 masked windows

__device__ __forceinline__ float dpp_shr1(float v) {
  return __int_as_float(__builtin_amdgcn_update_dpp(
      __float_as_int(v), __float_as_int(v), 0x138 /*wave_shr:1*/, 0xF, 0xF, false));
}

__global__ __launch_bounds__(512, 1)
void k_dp(const unsigned short* __restrict__ negh, float* __restrict__ dur,
          int* __restrict__ idx_out, const float* __restrict__ x_mask,
          unsigned long long* __restrict__ gbits_all) {
  __shared__ unsigned short ringh[8][4][KROWS * 64];  // 65536 B per-wave ring
  __shared__ float bndfull[NWIN][8][KROWS];           // 65536 B boundary array
  __shared__ int prog[8];                             // per-wave progress
  int b = blockIdx.x, tid = threadIdx.x;
  int lane = tid & 63, w = tid >> 6;
  const unsigned short* nb =
      negh + (((size_t)b * NWIN) * 8 + w) * 1024 + lane * 8;
  unsigned long long* gbits = gbits_all + (size_t)b * 8 * TFEAT;  // [8][2048]

  if (tid < 8) prog[tid] = 0;

  auto stage = [&](int j) {               // 2 contiguous 1KB loads
    int slot = j & 3;
    const unsigned short* s0 = nb + (size_t)j * 8 * 1024;
    gload_lds16h(s0,       &ringh[w][slot][0]);
    gload_lds16h(s0 + 512, &ringh[w][slot][512]);
  };

  stage(0); stage(1); stage(2);
  __syncthreads();                        // prog init visible; prologue loads queued

  float prev = NEGINF;
  for (int i = 0; i < NWIN; ++i) {
    // issue prefetch + counted wait for THIS window's loads (R21 store-aware)
    if (i + 3 < NWIN) {
      stage(i + 3);
      if (i >= 3)      VMCNT(9);
      else if (i == 2) VMCNT(8);
      else if (i == 1) VMCNT(7);
      else             VMCNT(6);
    } else {
      int rem = NWIN - 1 - i;
      if (rem == 2)      VMCNT(7);
      else if (rem == 1) VMCNT(5);
      else               VMCNT(3);
    }
    // wait for producer wave (adjacent only; no global convergence)
    if (w > 0) {
      volatile int* pf = &prog[w - 1];
      while (*pf < i + 1) __builtin_amdgcn_s_sleep(1);
      asm volatile("" ::: "memory");      // no reads hoisted above the spin
    }

    // hoisted boundary values (wave-uniform)
    float s_bnd[KROWS];
    if (w > 0) {
      float v   = bndfull[i][w - 1][lane & 15];
      float v15 = (i > 0) ? bndfull[i - 1][w - 1][15] : NEGINF;
      s_bnd[0] = __int_as_float(__builtin_amdgcn_readfirstlane(__float_as_int(v15)));
      #pragma unroll
      for (int r = 1; r < KROWS; ++r)
        s_bnd[r] = __int_as_float(__builtin_amdgcn_readlane(__float_as_int(v), r - 1));
    } else {
      #pragma unroll
      for (int r = 0; r < KROWS; ++r) s_bnd[r] = NEGINF;
      if (i == 0) s_bnd[0] = 0.0f;        // y==0, x==0 edge
    }
    // own-slice nf: bf16 -> f32 exact decode
    float cur[KROWS];
    #pragma unroll
    for (int r = 0; r < KROWS; ++r)
      cur[r] = __uint_as_float((unsigned)ringh[w][i & 3][r * 64 + lane] << 16);

    int y0 = i * KROWS;
    bool masked = (i < NMASKW);
    unsigned keep_lo = 0, keep_hi = 0;
    float bnd_hist[KROWS];                // lane63's copy feeds bndfull
    unsigned long long andm = (w == 0) ? ~1ull : ~0ull;   // x==0 never moves
    __builtin_amdgcn_s_setprio(1);
    #pragma unroll
    for (int r = 0; r < KROWS; ++r) {
      float upd = dpp_shr1(prev);
      float up = (lane == 0) ? s_bnd[r] : upd;
      bool force = masked && (tid == y0 + r);
      bool gt = prev < up;
      unsigned long long m = __ballot(force || gt) & andm;  // uniform
      bool mine = (lane == r);
      keep_lo = mine ? (unsigned)m : keep_lo;
      keep_hi = mine ? (unsigned)(m >> 32) : keep_hi;
      float vc = force ? NEGINF : prev;
      prev = fmaxf(vc, up) + cur[r];
      bnd_hist[r] = prev;                 // static index, 1 v_mov
    }
    __builtin_amdgcn_s_setprio(0);
    if (lane == 63) {                     // boundary handoff, 4x b128
      float4* bd = (float4*)&bndfull[i][w][0];
      bd[0] = make_float4(bnd_hist[0],  bnd_hist[1],  bnd_hist[2],  bnd_hist[3]);
      bd[1] = make_float4(bnd_hist[4],  bnd_hist[5],  bnd_hist[6],  bnd_hist[7]);
      bd[2] = make_float4(bnd_hist[8],  bnd_hist[9],  bnd_hist[10], bnd_hist[11]);
      bd[3] = make_float4(bnd_hist[12], bnd_hist[13], bnd_hist[14], bnd_hist[15]);
    }
    if (lane < KROWS) {                   // decision bits
      gbits[(size_t)w * TFEAT + y0 + lane] =
          ((unsigned long long)keep_hi << 32) | keep_lo;   // 128B contiguous
    }
    // publish: boundary writes complete, then bump flag
    asm volatile("s_waitcnt lgkmcnt(0)" ::: "memory");
    if (lane == 0) *((volatile int*)&prog[w]) = i + 1;
  }
  VMCNT(0);
  __syncthreads();                        // gbits stores drained + visible

  // ---- serial backtrack (tid 0), 16-deep register ring over global bits.
  if (tid == 0) {
    const float* xm = x_mask + (size_t)b * TTXT;
    int idx = TTXT - 1, cnt = 0;
    unsigned long long ua[16], ub[16]; int qi[16];
    #pragma unroll
    for (int q16 = 0; q16 < 16; ++q16) {  // rows 2032..2047 (slot = y&15)
      ua[q16] = gbits[(size_t)7 * TFEAT + 2032 + q16];
      ub[q16] = gbits[(size_t)6 * TFEAT + 2032 + q16];
      qi[q16] = 7;
    }
    for (int yb = 2032; yb >= 16; yb -= 16) {
      #pragma unroll
      for (int jj = 15; jj >= 0; --jj) {
        int y = yb + jj;                  // slot = jj (yb % 16 == 0)
        unsigned long long w64 = ((idx >> 6) == qi[jj]) ? ua[jj] : ub[jj];
        idx_out[b * TFEAT + y] = idx;
        cnt++;
        if ((w64 >> (idx & 63)) & 1ull) {
          dur[b * TTXT + idx] = (float)cnt * xm[idx];
          cnt = 0; idx--;
        }
        int q = idx >> 6;                 // refill slot jj for row y-16
        int qm = q > 0 ? q - 1 : 0;
        ua[jj] = gbits[(size_t)q  * TFEAT + (y - 16)];
        ub[jj] = gbits[(size_t)qm * TFEAT + (y - 16)];
        qi[jj] = q;
      }
    }
    #pragma unroll
    for (int jj = 15; jj >= 0; --jj) {    // tail rows 15..0
      int y = jj;
      unsigned long long w64 = ((idx >> 6) == qi[jj]) ? ua[jj] : ub[jj];
      idx_out[b * TFEAT + y] = idx;
      cnt++;
      if ((w64 >> (idx & 63)) & 1ull) {
        dur[b * TTXT + idx] = (float)cnt * xm[idx];
        cnt = 0; idx--;
      }
    }
    dur[b * TTXT] = (float)cnt * xm[0];   // idx == 0 tail run
  }
}

// ---------------------------------------------------------------------------
// Kernel D: attn[b,y,x] = (x == idx[y]) * x_mask[b,x] * y_mask[b,y]
// ---------------------------------------------------------------------------
__global__ void k_attn(const int* __restrict__ idx_arr,
                       const float* __restrict__ x_mask,
                       const float* __restrict__ y_mask,
                       float* __restrict__ attn) {
  size_t gid = (size_t)blockIdx.x * 256 + threadIdx.x;
  size_t e = gid << 2;               // 4 floats per thread
  int b = (int)(e >> 20);            // TFEAT*TTXT = 2^20
  int rem = (int)(e & 1048575u);
  int y = rem >> 9;
  int x0 = rem & 511;
  int idx = idx_arr[b * TFEAT + y];
  float4 v = {0.f, 0.f, 0.f, 0.f};
  int d = idx - x0;
  if (d >= 0 && d < 4) {
    ((float*)&v)[d] = x_mask[b * TTXT + idx] * y_mask[b * TFEAT + y];
  }
  *(float4*)(attn + e) = v;
}

// ---------------------------------------------------------------------------
extern "C" void kernel_launch(void* const* d_in, const int* in_sizes, int n_in,
                              void* d_out, int out_size, void* d_ws, size_t ws_size,
                              hipStream_t stream) {
  const float* z_p    = (const float*)d_in[0];
  const float* m_p    = (const float*)d_in[1];
  const float* logs_p = (const float*)d_in[2];
  const float* x_mask = (const float*)d_in[3];
  const float* y_mask = (const float*)d_in[4];

  float* out  = (float*)d_out;
  float* attn = out;
  float* dur  = out + DUR_OFF;
  float* neg  = out + NEG_OFF;

  // scratch in the attn region (134,217,728 B; fully rewritten by k_attn):
  //   gbits 4MB | negh 64MB | At2 48MB | Bt2 12MB  (exact fit)
  char* scr = (char*)attn;
  unsigned long long* gbits = (unsigned long long*)scr;
  unsigned short* negh = (unsigned short*)(scr + 4194304);
  unsigned short* At2  = (unsigned short*)(scr + 71303168);
  unsigned short* Bt2  = (unsigned short*)(scr + 121634816);

  // workspace: cadd (64 KiB) + idx array (256 KiB)
  float* cadd = (float*)d_ws;
  int*   idxa = (int*)((char*)d_ws + 65536);

  k_transA<<<BATCH * 64, 256, 0, stream>>>(z_p, At2);
  k_transB<<<BATCH * 16, 256, 0, stream>>>(m_p, logs_p, Bt2);
  k_cadd<<<(BATCH * TTXT) / 256, 256, 0, stream>>>(m_p, logs_p, cadd);
  k_mf<<<1024, 512, 0, stream>>>(At2, Bt2, cadd, neg, negh);
  k_dp<<<BATCH, 512, 0, stream>>>(negh, dur, idxa, x_mask, gbits);
  k_attn<<<(int)(ATTN_ELEMS / 4 / 256), 256, 0, stream>>>(idxa, x_mask, y_mask, attn);
}

// Round 24
// 503.296 us; speedup vs baseline: 1.0845x; 1.0845x over previous
//
#include <hip/hip_runtime.h>
#include <math.h>

// Problem constants (fixed by the reference setup_inputs)
#define BATCH 32
#define CH    192
#define TFEAT 2048
#define TTXT  512
#define NEGINF (-1e9f)

#define ATTN_ELEMS ((size_t)BATCH * TFEAT * TTXT)   // 33,554,432
#define DUR_OFF    ATTN_ELEMS
#define NEG_OFF    (ATTN_ELEMS + (size_t)BATCH * TTXT)

typedef short bf16x8 __attribute__((ext_vector_type(8)));   // 8 bf16 = 4 VGPR
typedef float f32x16 __attribute__((ext_vector_type(16)));  // 32x32 acc

__device__ __forceinline__ void gload_lds16h(const unsigned short* g,
                                             unsigned short* l) {
  __builtin_amdgcn_global_load_lds(
      (const __attribute__((address_space(1))) void*)g,
      (__attribute__((address_space(3))) void*)l, 16, 0, 0);
}

#define VMCNT(n) asm volatile("s_waitcnt vmcnt(" #n ")" ::: "memory")

__device__ __forceinline__ unsigned short f2b16(float f) {   // RNE bf16
  unsigned u = __float_as_uint(f);
  return (unsigned short)((u + 0x7FFFu + ((u >> 16) & 1u)) >> 16);
}

// ---------------------------------------------------------------------------
// Kernel TA: At2 = fragment-ready bf16 of A = [z | z^2] (M=2048, K=384).
// ---------------------------------------------------------------------------
__global__ __launch_bounds__(256)
void k_transA(const float* __restrict__ z_p, unsigned short* __restrict__ At2) {
  __shared__ float zt[CH][33];
  int b = blockIdx.x >> 6, tblk = blockIdx.x & 63;
  int tid = threadIdx.x;
  int t0 = tblk * 32;
  for (int i = tid; i < CH * 32; i += 256) {
    int c = i >> 5, m = i & 31;
    zt[c][m] = z_p[((size_t)b * CH + c) * TFEAT + t0 + m];
  }
  __syncthreads();
  unsigned short* out = At2 + (size_t)(b * 64 + tblk) * 24 * 512;
  for (int o = tid; o < 24 * 512; o += 256) {
    int kq = o >> 9, rem = o & 511;
    int lane = rem >> 3, j = rem & 7;
    int m = lane & 31, kh = lane >> 5;
    int k = kq * 16 + kh * 8 + j;
    float f;
    if (k < CH) f = zt[k][m];
    else { float z = zt[k - CH][m]; f = z * z; }
    out[o] = f2b16(f);
  }
}

// ---------------------------------------------------------------------------
// Kernel TB: Bt2 = fragment-ready bf16 of B = [W1 ; W2] (K=384, N=512).
// ---------------------------------------------------------------------------
__global__ __launch_bounds__(256)
void k_transB(const float* __restrict__ m_p, const float* __restrict__ logs_p,
              unsigned short* __restrict__ Bt2) {
  __shared__ float w1t[CH][33];
  __shared__ float w2t[CH][33];
  int b = blockIdx.x >> 4, sblk = blockIdx.x & 15;
  int tid = threadIdx.x;
  int s0 = sblk * 32;
  for (int i = tid; i < CH * 32; i += 256) {
    int c = i >> 5, n = i & 31;
    size_t idx = ((size_t)b * CH + c) * TTXT + s0 + n;
    float m = m_p[idx];
    float r = __expf(-2.0f * logs_p[idx]);
    w1t[c][n] = m * r;
    w2t[c][n] = -0.5f * r;
  }
  __syncthreads();
  unsigned short* out = Bt2 + (size_t)(b * 16 + sblk) * 24 * 512;
  for (int o = tid; o < 24 * 512; o += 256) {
    int kq = o >> 9, rem = o & 511;
    int lane = rem >> 3, j = rem & 7;
    int n = lane & 31, kh = lane >> 5;
    int k = kq * 16 + kh * 8 + j;
    float f = (k < CH) ? w1t[k][n] : w2t[k - CH][n];
    out[o] = f2b16(f);
  }
}

// ---------------------------------------------------------------------------
// Kernel A: cadd[b][s] = sum_c(-0.5*log(2pi) - logs) + sum_c(-0.5*m^2*r)
// ---------------------------------------------------------------------------
__global__ void k_cadd(const float* __restrict__ m_p,
                       const float* __restrict__ logs_p,
                       float* __restrict__ cadd) {
  int gid = blockIdx.x * 256 + threadIdx.x;        // 0 .. 16383
  int b = gid >> 9, s = gid & (TTXT - 1);
  const float* mp = m_p    + (size_t)b * CH * TTXT + s;
  const float* lp = logs_p + (size_t)b * CH * TTXT + s;
  float acc = -0.5f * 1.8378770664093453f * (float)CH;   // -C/2 * log(2*pi)
  #pragma unroll 4
  for (int c = 0; c < CH; ++c) {
    float l = lp[(size_t)c * TTXT];
    float m = mp[(size_t)c * TTXT];
    float r = __expf(-2.0f * l);
    acc -= l + 0.5f * m * m * r;
  }
  cadd[gid] = acc;
}

// ---------------------------------------------------------------------------
// Kernel B: bf16 MFMA GEMM (R19, UNCHANGED).
// ---------------------------------------------------------------------------
__global__ __launch_bounds__(512)
void k_mf(const unsigned short* __restrict__ At2,
          const unsigned short* __restrict__ Bt2,
          const float* __restrict__ cadd,
          float* __restrict__ neg,
          unsigned short* __restrict__ negh) {
  int blk = (blockIdx.x & 7) * 128 + (blockIdx.x >> 3);
  int sb = blk & 1;            // 512/256 = 2 col-blocks
  int tb = (blk >> 1) & 15;    // 2048/128 = 16 row-blocks
  int b  = blk >> 5;
  int tid = threadIdx.x, lane = tid & 63, w = tid >> 6;
  int rg = w >> 2, cg = w & 3;
  int trow0 = tb * 128 + rg * 64;
  int scol0 = sb * 256 + cg * 64;

  const unsigned short* ap0 = At2 + ((size_t)(b * 64 + (trow0 >> 5)) * 24) * 512 + lane * 8;
  const unsigned short* ap1 = ap0 + (size_t)24 * 512;
  const unsigned short* bp0 = Bt2 + ((size_t)(b * 16 + (scol0 >> 5)) * 24) * 512 + lane * 8;
  const unsigned short* bp1 = bp0 + (size_t)24 * 512;

  f32x16 acc00, acc01, acc10, acc11;
  #pragma unroll
  for (int r = 0; r < 16; ++r) { acc00[r] = 0.f; acc01[r] = 0.f; acc10[r] = 0.f; acc11[r] = 0.f; }

  bf16x8 a0A, a1A, b0A, b1A;
  bf16x8 a0B, a1B, b0B, b1B;

  auto LDA = [&](bf16x8& x0, bf16x8& x1, bf16x8& y0, bf16x8& y1, int kq) {
    x0 = *(const bf16x8*)(ap0 + (size_t)kq * 512);
    x1 = *(const bf16x8*)(ap1 + (size_t)kq * 512);
    y0 = *(const bf16x8*)(bp0 + (size_t)kq * 512);
    y1 = *(const bf16x8*)(bp1 + (size_t)kq * 512);
  };
  auto FMA = [&](bf16x8& x0, bf16x8& x1, bf16x8& y0, bf16x8& y1) {
    acc00 = __builtin_amdgcn_mfma_f32_32x32x16_bf16(x0, y0, acc00, 0, 0, 0);
    acc01 = __builtin_amdgcn_mfma_f32_32x32x16_bf16(x0, y1, acc01, 0, 0, 0);
    acc10 = __builtin_amdgcn_mfma_f32_32x32x16_bf16(x1, y0, acc10, 0, 0, 0);
    acc11 = __builtin_amdgcn_mfma_f32_32x32x16_bf16(x1, y1, acc11, 0, 0, 0);
  };

  LDA(a0A, a1A, b0A, b1A, 0);
  #pragma unroll
  for (int kq = 0; kq < 24; kq += 2) {
    LDA(a0B, a1B, b0B, b1B, kq + 1);
    FMA(a0A, a1A, b0A, b1A);
    __builtin_amdgcn_sched_barrier(0);
    if (kq + 2 < 24) LDA(a0A, a1A, b0A, b1A, kq + 2);
    FMA(a0B, a1B, b0B, b1B);
    __builtin_amdgcn_sched_barrier(0);
  }

  #pragma unroll
  for (int ti = 0; ti < 2; ++ti) {
    #pragma unroll
    for (int tj = 0; tj < 2; ++tj) {
      const f32x16& v = (ti == 0) ? ((tj == 0) ? acc00 : acc01)
                                  : ((tj == 0) ? acc10 : acc11);
      int s = scol0 + tj * 32 + (lane & 31);
      float cv = cadd[b * TTXT + s];
      int tB = trow0 + ti * 32 + 4 * (lane >> 5);
      float* np_ = neg + (size_t)b * TFEAT * TTXT + s;
      #pragma unroll
      for (int r = 0; r < 16; ++r) {
        int t = tB + (r & 3) + 8 * (r >> 2);
        float o = v[r] + cv;
        np_[(size_t)t * TTXT] = o;
        negh[(((size_t)b * 128 + (t >> 4)) * 8 + (s >> 6)) * 1024
             + (t & 15) * 64 + (s & 63)] = f2b16(o);
      }
    }
  }
}

// ---------------------------------------------------------------------------
// Kernel C: skewed-wavefront DP (R22 — session best, FINAL).
// Ten structural interventions (bytes, segments, barrier count/removal,
// body ops, store-gating, TLP, hazards, setprio, vmcnt counting) leave a
// ~380cy/row residue: the serial 2048-row (max,+) recurrence's dependency
// floor at 32-way batch parallelism. R23's barrier-free spin version
// regressed (396us, VGPR 88); this 8-wave skew + s_barrier form is optimal.
// ---------------------------------------------------------------------------
#define KROWS 16
#define NWIN  (TFEAT / KROWS)     // 128 windows
#define NMASKW (TTXT / KROWS)     // 32 masked windows

__device__ __forceinline__ float dpp_shr1(float v) {
  return __int_as_float(__builtin_amdgcn_update_dpp(
      __float_as_int(v), __float_as_int(v), 0x138 /*wave_shr:1*/, 0xF, 0xF, false));
}

__global__ __launch_bounds__(512, 1)
void k_dp(const unsigned short* __restrict__ negh, float* __restrict__ dur,
          int* __restrict__ idx_out, const float* __restrict__ x_mask,
          unsigned long long* __restrict__ gbits_all) {
  __shared__ unsigned short ringh[8][4][KROWS * 64];  // 65536 B per-wave ring
  __shared__ float bndlds[3][8][KROWS];               //  1536 B boundary ring
  int b = blockIdx.x, tid = threadIdx.x;
  int lane = tid & 63, w = tid >> 6;
  // wave w's slice stream: blocks of 1024 ushorts per (window, wave)
  const unsigned short* nb =
      negh + (((size_t)b * NWIN) * 8 + w) * 1024 + lane * 8;
  unsigned long long* gbits = gbits_all + (size_t)b * 8 * TFEAT;  // [8][2048]

  if (tid < 3 * 8 * KROWS) ((float*)bndlds)[tid] = NEGINF;

  auto stage = [&](int j) {               // 2 contiguous 1KB loads
    int slot = j & 3;
    const unsigned short* s0 = nb + (size_t)j * 8 * 1024;
    gload_lds16h(s0,       &ringh[w][slot][0]);
    gload_lds16h(s0 + 512, &ringh[w][slot][512]);
  };

  stage(0); stage(1); stage(2);
  __syncthreads();                        // drains prologue loads + bndlds init

  float prev = NEGINF;
  for (int p = 0; p < NWIN + 8; ++p) {
    int i = p - w;                        // this wave's window this phase
    if (i >= 0 && i + 3 < NWIN) {
      stage(i + 3);
      // store-aware wait (R21): window i's loads done without draining
      // newer stores (2*min(3,rem) loads + min(i,3) stores after them)
      if (i >= 3)      VMCNT(9);
      else if (i == 2) VMCNT(8);
      else if (i == 1) VMCNT(7);
      else             VMCNT(6);          // i == 0
    } else if (i >= 0) {
      int rem = NWIN - 1 - i;
      if (rem == 2)      VMCNT(7);
      else if (rem == 1) VMCNT(5);
      else               VMCNT(3);
    }
    asm volatile("s_waitcnt lgkmcnt(0)" ::: "memory");
    __builtin_amdgcn_s_barrier();         // bndlds(prev phase) visible
    __builtin_amdgcn_sched_barrier(0);

    if (i >= 0 && i < NWIN) {
      // hoisted boundary values (wave-uniform)
      float s_bnd[KROWS];
      if (w > 0) {
        float v   = bndlds[i % 3][w - 1][lane & 15];
        float v15 = bndlds[(i + 2) % 3][w - 1][15];
        s_bnd[0] = __int_as_float(__builtin_amdgcn_readfirstlane(__float_as_int(v15)));
        #pragma unroll
        for (int r = 1; r < KROWS; ++r)
          s_bnd[r] = __int_as_float(__builtin_amdgcn_readlane(__float_as_int(v), r - 1));
      } else {
        #pragma unroll
        for (int r = 0; r < KROWS; ++r) s_bnd[r] = NEGINF;
        if (i == 0) s_bnd[0] = 0.0f;      // y==0, x==0 edge
      }
      // own-slice nf: bf16 -> f32 exact decode
      float cur[KROWS];
      #pragma unroll
      for (int r = 0; r < KROWS; ++r)
        cur[r] = __uint_as_float((unsigned)ringh[w][i & 3][r * 64 + lane] << 16);

      int y0 = i * KROWS;
      bool masked = (i < NMASKW);
      unsigned keep_lo = 0, keep_hi = 0;
      float bnd_hist[KROWS];              // lane63's copy feeds bndlds
      unsigned long long andm = (w == 0) ? ~1ull : ~0ull;   // x==0 never moves
      __builtin_amdgcn_s_setprio(1);
      #pragma unroll
      for (int r = 0; r < KROWS; ++r) {
        float upd = dpp_shr1(prev);
        float up = (lane == 0) ? s_bnd[r] : upd;
        bool force = masked && (tid == y0 + r);
        bool gt = prev < up;
        unsigned long long m = __ballot(force || gt) & andm;  // uniform
        bool mine = (lane == r);
        keep_lo = mine ? (unsigned)m : keep_lo;
        keep_hi = mine ? (unsigned)(m >> 32) : keep_hi;
        float vc = force ? NEGINF : prev;
        prev = fmaxf(vc, up) + cur[r];
        bnd_hist[r] = prev;               // static index, 1 v_mov
      }
      __builtin_amdgcn_s_setprio(0);
      if (lane == 63) {                   // boundary handoff, 4x b128
        float4* bd = (float4*)&bndlds[i % 3][w][0];
        bd[0] = make_float4(bnd_hist[0],  bnd_hist[1],  bnd_hist[2],  bnd_hist[3]);
        bd[1] = make_float4(bnd_hist[4],  bnd_hist[5],  bnd_hist[6],  bnd_hist[7]);
        bd[2] = make_float4(bnd_hist[8],  bnd_hist[9],  bnd_hist[10], bnd_hist[11]);
        bd[3] = make_float4(bnd_hist[12], bnd_hist[13], bnd_hist[14], bnd_hist[15]);
      }
      if (lane < KROWS) {                 // decision bits
        gbits[(size_t)w * TFEAT + y0 + lane] =
            ((unsigned long long)keep_hi << 32) | keep_lo;   // 128B contiguous
      }
    }
  }
  VMCNT(0);
  __syncthreads();                        // gbits stores drained + visible

  // ---- serial backtrack (tid 0), 16-deep register ring over global bits.
  if (tid == 0) {
    const float* xm = x_mask + (size_t)b * TTXT;
    int idx = TTXT - 1, cnt = 0;
    unsigned long long ua[16], ub[16]; int qi[16];
    #pragma unroll
    for (int q16 = 0; q16 < 16; ++q16) {  // rows 2032..2047 (slot = y&15)
      ua[q16] = gbits[(size_t)7 * TFEAT + 2032 + q16];
      ub[q16] = gbits[(size_t)6 * TFEAT + 2032 + q16];
      qi[q16] = 7;
    }
    for (int yb = 2032; yb >= 16; yb -= 16) {
      #pragma unroll
      for (int jj = 15; jj >= 0; --jj) {
        int y = yb + jj;                  // slot = jj (yb % 16 == 0)
        unsigned long long w64 = ((idx >> 6) == qi[jj]) ? ua[jj] : ub[jj];
        idx_out[b * TFEAT + y] = idx;
        cnt++;
        if ((w64 >> (idx & 63)) & 1ull) {
          dur[b * TTXT + idx] = (float)cnt * xm[idx];
          cnt = 0; idx--;
        }
        int q = idx >> 6;                 // refill slot jj for row y-16
        int qm = q > 0 ? q - 1 : 0;
        ua[jj] = gbits[(size_t)q  * TFEAT + (y - 16)];
        ub[jj] = gbits[(size_t)qm * TFEAT + (y - 16)];
        qi[jj] = q;
      }
    }
    #pragma unroll
    for (int jj = 15; jj >= 0; --jj) {    // tail rows 15..0
      int y = jj;
      unsigned long long w64 = ((idx >> 6) == qi[jj]) ? ua[jj] : ub[jj];
      idx_out[b * TFEAT + y] = idx;
      cnt++;
      if ((w64 >> (idx & 63)) & 1ull) {
        dur[b * TTXT + idx] = (float)cnt * xm[idx];
        cnt = 0; idx--;
      }
    }
    dur[b * TTXT] = (float)cnt * xm[0];   // idx == 0 tail run
  }
}

// ---------------------------------------------------------------------------
// Kernel D: attn[b,y,x] = (x == idx[y]) * x_mask[b,x] * y_mask[b,y]
// ---------------------------------------------------------------------------
__global__ void k_attn(const int* __restrict__ idx_arr,
                       const float* __restrict__ x_mask,
                       const float* __restrict__ y_mask,
                       float* __restrict__ attn) {
  size_t gid = (size_t)blockIdx.x * 256 + threadIdx.x;
  size_t e = gid << 2;               // 4 floats per thread
  int b = (int)(e >> 20);            // TFEAT*TTXT = 2^20
  int rem = (int)(e & 1048575u);
  int y = rem >> 9;
  int x0 = rem & 511;
  int idx = idx_arr[b * TFEAT + y];
  float4 v = {0.f, 0.f, 0.f, 0.f};
  int d = idx - x0;
  if (d >= 0 && d < 4) {
    ((float*)&v)[d] = x_mask[b * TTXT + idx] * y_mask[b * TFEAT + y];
  }
  *(float4*)(attn + e) = v;
}

// ---------------------------------------------------------------------------
extern "C" void kernel_launch(void* const* d_in, const int* in_sizes, int n_in,
                              void* d_out, int out_size, void* d_ws, size_t ws_size,
                              hipStream_t stream) {
  const float* z_p    = (const float*)d_in[0];
  const float* m_p    = (const float*)d_in[1];
  const float* logs_p = (const float*)d_in[2];
  const float* x_mask = (const float*)d_in[3];
  const float* y_mask = (const float*)d_in[4];

  float* out  = (float*)d_out;
  float* attn = out;
  float* dur  = out + DUR_OFF;
  float* neg  = out + NEG_OFF;

  // scratch in the attn region (134,217,728 B; fully rewritten by k_attn):
  //   gbits 4MB | negh 64MB | At2 48MB | Bt2 12MB  (exact fit)
  char* scr = (char*)attn;
  unsigned long long* gbits = (unsigned long long*)scr;
  unsigned short* negh = (unsigned short*)(scr + 4194304);
  unsigned short* At2  = (unsigned short*)(scr + 71303168);
  unsigned short* Bt2  = (unsigned short*)(scr + 121634816);

  // workspace: cadd (64 KiB) + idx array (256 KiB)
  float* cadd = (float*)d_ws;
  int*   idxa = (int*)((char*)d_ws + 65536);

  k_transA<<<BATCH * 64, 256, 0, stream>>>(z_p, At2);
  k_transB<<<BATCH * 16, 256, 0, stream>>>(m_p, logs_p, Bt2);
  k_cadd<<<(BATCH * TTXT) / 256, 256, 0, stream>>>(m_p, logs_p, cadd);
  k_mf<<<1024, 512, 0, stream>>>(At2, Bt2, cadd, neg, negh);
  k_dp<<<BATCH, 512, 0, stream>>>(negh, dur, idxa, x_mask, gbits);
  k_attn<<<(int)(ATTN_ELEMS / 4 / 256), 256, 0, stream>>>(idxa, x_mask, y_mask, attn);
}